// Round 9
// baseline (120.838 us; speedup 1.0000x reference)
//
#include <hip/hip_runtime.h>

using f32x4 = __attribute__((ext_vector_type(4))) float;
using s16x8 = __attribute__((ext_vector_type(8))) short;

constexpr int B = 4, T = 1024, H = 12, D = 64;
constexpr int LD = 72;   // LDS row stride (bf16 elems): 144B -> 2-way bank aliasing (free), 16B-aligned

__device__ __forceinline__ short f2bf(float f) {        // RNE
    unsigned u = __float_as_uint(f);
    u = (u + 0x7fffu + ((u >> 16) & 1u)) >> 16;
    return (short)u;
}
__device__ __forceinline__ short f2bf_trunc(float f) {  // truncate (p >= 0)
    return (short)(__float_as_uint(f) >> 16);
}

// ---------------------------------------------------------------------------
// Kernel 0: W prep. wt_ws[h][o][i] = W[route(h)][i][o] * (o<64 ? 0.125*log2e : 1)
// ---------------------------------------------------------------------------
__global__ __launch_bounds__(256) void wprep_kernel(
    const float* __restrict__ W, const int* __restrict__ s2h,
    short* __restrict__ wt_ws)
{
    __shared__ float tile[64][68];
    const int h = blockIdx.x, ot = blockIdx.y;          // (12, 3)
    const int kk = h >> 2, m = s2h[h];
    const float* Wp = W + (size_t)(kk * 4 + m) * D * 192 + ot * 64;
    const float qs = (ot == 0) ? 0.125f * 1.44269504f : 1.0f;
    const int tid = threadIdx.x;
    for (int e = tid; e < 1024; e += 256) {
        const int i = e >> 4, o4 = e & 15;
        float4 v = *reinterpret_cast<const float4*>(Wp + (size_t)i * 192 + o4 * 4);
        tile[i][o4 * 4 + 0] = v.x * qs;
        tile[i][o4 * 4 + 1] = v.y * qs;
        tile[i][o4 * 4 + 2] = v.z * qs;
        tile[i][o4 * 4 + 3] = v.w * qs;
    }
    __syncthreads();
    short* op = wt_ws + (size_t)h * 192 * 64 + (size_t)ot * 64 * 64;
    for (int e = tid; e < 1024; e += 256) {
        const int o = e >> 4, i4 = e & 15;
        short4 s = make_short4(f2bf(tile[i4 * 4 + 0][o]), f2bf(tile[i4 * 4 + 1][o]),
                               f2bf(tile[i4 * 4 + 2][o]), f2bf(tile[i4 * 4 + 3][o]));
        *reinterpret_cast<short4*>(op + o * 64 + i4 * 4) = s;
    }
}

// ---------------------------------------------------------------------------
// Kernel 1: routed QKV projection, MFMA, LDS-roundtrip epilogue for fully
// coalesced stores. q,k -> [bh][T][64]; v -> chunk-tiled transpose
// [bh][ct=16][d=64][t=64]. q pre-scaled by 0.125*log2e (via wprep).
// ---------------------------------------------------------------------------
__global__ __launch_bounds__(256) void proj_kernel(
    const float* __restrict__ x, const short* __restrict__ wt_ws,
    short* __restrict__ qw, short* __restrict__ kw, short* __restrict__ vt)
{
    __shared__ short buf[64 * LD + 192 * LD];   // 36864 B, aliased stage/epilogue
    short* ax = buf;                 // stage: x tile [t][i]
    short* wt = buf + 64 * LD;       // stage: W^T    [o][i]
    short* eq = buf;                 // epi: q [t][d]
    short* ek = buf + 64 * LD;       // epi: k [t][d]
    short* ev = buf + 128 * LD;      // epi: v [d][t]

    const int h = blockIdx.y;
    const int tid = threadIdx.x;
    const int t0g = blockIdx.x * 64;
    const int b = t0g / T, t0 = t0g % T;
    const int bh = b * H + h;
    const int ct = t0 >> 6;

    const float* xp = x + ((size_t)(b * T + t0) * H + h) * D;
    for (int e4 = tid; e4 < 64 * 16; e4 += 256) {
        const int row = e4 >> 4, i4 = e4 & 15;
        float4 v = *reinterpret_cast<const float4*>(xp + (size_t)row * H * D + i4 * 4);
        *reinterpret_cast<short4*>(&ax[row * LD + i4 * 4]) =
            make_short4(f2bf(v.x), f2bf(v.y), f2bf(v.z), f2bf(v.w));
    }
    const short* wtp = wt_ws + (size_t)h * 192 * 64;
    for (int e8 = tid; e8 < 192 * 8; e8 += 256) {
        const int row = e8 >> 3, c8 = e8 & 7;
        *reinterpret_cast<uint4*>(&wt[row * LD + c8 * 8]) =
            *reinterpret_cast<const uint4*>(wtp + (size_t)row * 64 + c8 * 8);
    }
    __syncthreads();

    const int wv = tid >> 6, lane = tid & 63, quad = lane >> 4, c = lane & 15;
    s16x8 af[4][2];
    #pragma unroll
    for (int mb = 0; mb < 4; ++mb)
        #pragma unroll
        for (int ks = 0; ks < 2; ++ks)
            af[mb][ks] = *reinterpret_cast<const s16x8*>(
                &ax[(mb * 16 + c) * LD + ks * 32 + quad * 8]);

    f32x4 acc[4][3];
    #pragma unroll
    for (int mb = 0; mb < 4; ++mb)
        #pragma unroll
        for (int nb = 0; nb < 3; ++nb)
            acc[mb][nb] = (f32x4){0.f, 0.f, 0.f, 0.f};

    #pragma unroll
    for (int nb = 0; nb < 3; ++nb) {
        const int o16 = nb * 4 + wv;             // wave handles one q, k, v slice
        #pragma unroll
        for (int ks = 0; ks < 2; ++ks) {
            s16x8 bf = *reinterpret_cast<const s16x8*>(
                &wt[(o16 * 16 + c) * LD + ks * 32 + quad * 8]);
            #pragma unroll
            for (int mb = 0; mb < 4; ++mb)
                acc[mb][nb] = __builtin_amdgcn_mfma_f32_16x16x32_bf16(
                    af[mb][ks], bf, acc[mb][nb], 0, 0, 0);
        }
    }
    __syncthreads();   // stage buffers dead; reuse LDS for epilogue

    const int d = wv * 16 + c;
    #pragma unroll
    for (int mb = 0; mb < 4; ++mb) {
        #pragma unroll
        for (int reg = 0; reg < 4; ++reg) {
            const int tl = mb * 16 + quad * 4 + reg;
            eq[tl * LD + d] = f2bf(acc[mb][0][reg]);
            ek[tl * LD + d] = f2bf(acc[mb][1][reg]);
        }
        short4 sv = make_short4(f2bf(acc[mb][2][0]), f2bf(acc[mb][2][1]),
                                f2bf(acc[mb][2][2]), f2bf(acc[mb][2][3]));
        *reinterpret_cast<short4*>(&ev[d * LD + mb * 16 + quad * 4]) = sv;
    }
    __syncthreads();

    // coalesced stores: a row is 64 shorts = 128 B = EIGHT 16B segments.
    for (int e = tid; e < 512; e += 256) {
        const int r = e >> 3, seg = e & 7;
        uint4 vq = *reinterpret_cast<const uint4*>(&eq[r * LD + seg * 8]);
        uint4 vk = *reinterpret_cast<const uint4*>(&ek[r * LD + seg * 8]);
        uint4 vv = *reinterpret_cast<const uint4*>(&ev[r * LD + seg * 8]);
        *reinterpret_cast<uint4*>(qw + ((size_t)bh * T + t0 + r) * 64 + seg * 8) = vq;
        *reinterpret_cast<uint4*>(kw + ((size_t)bh * T + t0 + r) * 64 + seg * 8) = vk;
        *reinterpret_cast<uint4*>(vt + (((size_t)bh * 16 + ct) * 64 + r) * 64 + seg * 8) = vv;
    }
}

// ---------------------------------------------------------------------------
// Kernel 2: causal attention. Transposed-score MFMA (S^T = K·Q^T), static-max
// base-2 softmax (p = 2^(s'-8)), R7's single-buffered K/V LDS staging.
// Block = 2 waves x 32 q-rows (two 16-row tiles per wave): K A-frags and V
// B-frags are loaded ONCE per wave-chunk and feed both tiles' MFMAs.
// ---------------------------------------------------------------------------
__global__ __launch_bounds__(128) void attn_kernel(
    const short* __restrict__ qw, const short* __restrict__ kw,
    const short* __restrict__ vt, float* __restrict__ out)
{
    __shared__ short lk[64 * LD];        // 9216 B : K chunk   [s][d]
    __shared__ short lv[64 * LD];        // 9216 B : V^T chunk [d][s]
    __shared__ short lp[2][32 * LD];     // 9216 B : P, wave-private [r][s]

    const int idx = blockIdx.x;
    const int bh = idx % 48;
    const int qt = ((idx / 48) * 11) & 15;   // balances co-resident block sets
    const int b = bh / H, h = bh % H;
    const int tid = threadIdx.x, wv = tid >> 6, lane = tid & 63;
    const int quad = lane >> 4, c = lane & 15;
    const int r0 = qt * 64;

    // Q B-frags for the wave's two 16-row tiles (contiguous 16B, once)
    s16x8 qf[2][2];
    #pragma unroll
    for (int rt = 0; rt < 2; ++rt) {
        const short* qp = qw + ((size_t)bh * T + r0 + wv * 32 + rt * 16 + c) * 64;
        qf[rt][0] = *reinterpret_cast<const s16x8*>(qp + quad * 8);
        qf[rt][1] = *reinterpret_cast<const s16x8*>(qp + 32 + quad * 8);
    }

    f32x4 oacc[2][4];
    #pragma unroll
    for (int rt = 0; rt < 2; ++rt)
        #pragma unroll
        for (int cb = 0; cb < 4; ++cb) oacc[rt][cb] = (f32x4){0.f, 0.f, 0.f, 0.f};
    float l_run[2] = {0.f, 0.f};
    short* lpw = lp[wv];

    for (int ch = 0; ch <= qt; ++ch) {
        __syncthreads();   // prior chunk's lk/lv reads complete before restage
        const short* kp = kw + ((size_t)bh * T + ch * 64) * 64;
        const short* vp = vt + (((size_t)bh * 16 + ch) * 64) * 64;
        for (int e8 = tid; e8 < 512; e8 += 128) {
            const int r = e8 >> 3, c8 = e8 & 7;
            *reinterpret_cast<uint4*>(&lk[r * LD + c8 * 8]) =
                *reinterpret_cast<const uint4*>(kp + r * 64 + c8 * 8);
            *reinterpret_cast<uint4*>(&lv[r * LD + c8 * 8]) =
                *reinterpret_cast<const uint4*>(vp + r * 64 + c8 * 8);
        }
        __syncthreads();

        // S^T tiles: rows s (quad*4+reg), cols r (c). A = K rows (shared by
        // both q-tiles), B = Q rows. Softmax applied per-st (sacc transient).
        const bool diag = (ch == qt);
        float lsum[2] = {0.f, 0.f};
        #pragma unroll
        for (int st = 0; st < 4; ++st) {
            s16x8 a0 = *reinterpret_cast<const s16x8*>(
                &lk[(st * 16 + c) * LD + quad * 8]);
            s16x8 a1 = *reinterpret_cast<const s16x8*>(
                &lk[(st * 16 + c) * LD + 32 + quad * 8]);
            #pragma unroll
            for (int rt = 0; rt < 2; ++rt) {
                f32x4 sacc = (f32x4){0.f, 0.f, 0.f, 0.f};
                sacc = __builtin_amdgcn_mfma_f32_16x16x32_bf16(a0, qf[rt][0], sacc, 0, 0, 0);
                sacc = __builtin_amdgcn_mfma_f32_16x16x32_bf16(a1, qf[rt][1], sacc, 0, 0, 0);
                if (diag) {
                    const int qloc = wv * 32 + rt * 16 + c;
                    #pragma unroll
                    for (int reg = 0; reg < 4; ++reg)
                        if (st * 16 + quad * 4 + reg > qloc) sacc[reg] = -1e30f;
                }
                float p0 = __builtin_amdgcn_exp2f(sacc[0] - 8.0f);
                float p1 = __builtin_amdgcn_exp2f(sacc[1] - 8.0f);
                float p2 = __builtin_amdgcn_exp2f(sacc[2] - 8.0f);
                float p3 = __builtin_amdgcn_exp2f(sacc[3] - 8.0f);
                lsum[rt] += (p0 + p1) + (p2 + p3);
                *reinterpret_cast<short4*>(&lpw[(rt * 16 + c) * LD + st * 16 + quad * 4]) =
                    make_short4(f2bf_trunc(p0), f2bf_trunc(p1),
                                f2bf_trunc(p2), f2bf_trunc(p3));
            }
        }
        #pragma unroll
        for (int rt = 0; rt < 2; ++rt) {
            float ls = lsum[rt];
            ls += __shfl_xor(ls, 16);
            ls += __shfl_xor(ls, 32);
            l_run[rt] += ls;               // full row-sum for q-row c of tile rt
        }

        // O += P V : A = P rows (same-wave DS in-order), B = V^T rows shared
        // across both tiles.
        #pragma unroll
        for (int ks2 = 0; ks2 < 2; ++ks2) {
            s16x8 pa0 = *reinterpret_cast<const s16x8*>(
                &lpw[c * LD + ks2 * 32 + quad * 8]);
            s16x8 pa1 = *reinterpret_cast<const s16x8*>(
                &lpw[(16 + c) * LD + ks2 * 32 + quad * 8]);
            #pragma unroll
            for (int cb = 0; cb < 4; ++cb) {
                s16x8 bf = *reinterpret_cast<const s16x8*>(
                    &lv[(cb * 16 + c) * LD + ks2 * 32 + quad * 8]);
                oacc[0][cb] = __builtin_amdgcn_mfma_f32_16x16x32_bf16(pa0, bf, oacc[0][cb], 0, 0, 0);
                oacc[1][cb] = __builtin_amdgcn_mfma_f32_16x16x32_bf16(pa1, bf, oacc[1][cb], 0, 0, 0);
            }
        }
    }

    // O rows are quad*4+reg; l for row r lives at lane index r (0..15)
    float linv[2][4];
    #pragma unroll
    for (int rt = 0; rt < 2; ++rt)
        #pragma unroll
        for (int reg = 0; reg < 4; ++reg)
            linv[rt][reg] = 1.0f / __shfl(l_run[rt], quad * 4 + reg);

    #pragma unroll
    for (int rt = 0; rt < 2; ++rt)
        #pragma unroll
        for (int cb = 0; cb < 4; ++cb)
            #pragma unroll
            for (int reg = 0; reg < 4; ++reg) {
                const int t = r0 + wv * 32 + rt * 16 + quad * 4 + reg;
                out[((size_t)(b * T + t) * H + h) * D + cb * 16 + c] =
                    oacc[rt][cb][reg] * linv[rt][reg];
            }
}

extern "C" void kernel_launch(void* const* d_in, const int* in_sizes, int n_in,
                              void* d_out, int out_size, void* d_ws, size_t ws_size,
                              hipStream_t stream) {
    const float* x   = (const float*)d_in[0];   // [B,T,K,N,D] fp32
    const float* W   = (const float*)d_in[1];   // [K,N,D,3D] fp32
    const int*   s2h = (const int*)d_in[2];     // [K,N] int32
    float* out = (float*)d_out;                 // [B,T,K,N,D] fp32

    short* wt_ws = (short*)d_ws;                       // [12][192][64] bf16
    short* qw    = wt_ws + (size_t)12 * 192 * 64;      // [bh][T][64] (pre-scaled)
    short* kw    = qw + (size_t)B * H * T * D;         // [bh][T][64]
    short* vt    = kw + (size_t)B * H * T * D;         // [bh][16][64][64] chunked V^T

    wprep_kernel<<<dim3(H, 3), 256, 0, stream>>>(W, s2h, wt_ws);
    proj_kernel<<<dim3(B * T / 64, H), 256, 0, stream>>>(x, wt_ws, qw, kw, vt);
    attn_kernel<<<dim3((T / 64) * (B * H)), 128, 0, stream>>>(qw, kw, vt, out);
}

// Round 10
// 103.046 us; speedup vs baseline: 1.1727x; 1.1727x over previous
//
#include <hip/hip_runtime.h>

using f32x4 = __attribute__((ext_vector_type(4))) float;
using s16x8 = __attribute__((ext_vector_type(8))) short;

constexpr int B = 4, T = 1024, H = 12, D = 64;
constexpr int LD = 72;   // LDS row stride (bf16 elems): 144B -> 2-way bank aliasing (free), 16B-aligned

__device__ __forceinline__ short f2bf(float f) {        // RNE
    unsigned u = __float_as_uint(f);
    u = (u + 0x7fffu + ((u >> 16) & 1u)) >> 16;
    return (short)u;
}
__device__ __forceinline__ short f2bf_trunc(float f) {  // truncate (p >= 0)
    return (short)(__float_as_uint(f) >> 16);
}

// Work units for attn: {qt, ch0, ch1, slot}; slot = -1 -> direct write to out,
// else partial index (qt-8)*2+part. qt>=8 split in two. Ordered by descending
// chunk count so heavy blocks dispatch first.
__device__ const int4 UNITS[24] = {
    {15,0,7,14},{15,8,15,15},{14,7,14,13},{7,0,7,-1},
    {14,0,6,12},{13,0,6,10},{13,7,13,11},{12,6,12,9},{6,0,6,-1},
    {12,0,5,8},{11,0,5,6},{11,6,11,7},{10,5,10,5},{5,0,5,-1},
    {10,0,4,4},{9,0,4,2},{9,5,9,3},{8,4,8,1},{4,0,4,-1},
    {8,0,3,0},{3,0,3,-1},{2,0,2,-1},{1,0,1,-1},{0,0,0,-1}
};

// ---------------------------------------------------------------------------
// Kernel 0: W prep. wt_ws[h][o][i] = W[route(h)][i][o] * (o<64 ? 0.125*log2e : 1)
// ---------------------------------------------------------------------------
__global__ __launch_bounds__(256) void wprep_kernel(
    const float* __restrict__ W, const int* __restrict__ s2h,
    short* __restrict__ wt_ws)
{
    __shared__ float tile[64][68];
    const int h = blockIdx.x, ot = blockIdx.y;          // (12, 3)
    const int kk = h >> 2, m = s2h[h];
    const float* Wp = W + (size_t)(kk * 4 + m) * D * 192 + ot * 64;
    const float qs = (ot == 0) ? 0.125f * 1.44269504f : 1.0f;
    const int tid = threadIdx.x;
    for (int e = tid; e < 1024; e += 256) {
        const int i = e >> 4, o4 = e & 15;
        float4 v = *reinterpret_cast<const float4*>(Wp + (size_t)i * 192 + o4 * 4);
        tile[i][o4 * 4 + 0] = v.x * qs;
        tile[i][o4 * 4 + 1] = v.y * qs;
        tile[i][o4 * 4 + 2] = v.z * qs;
        tile[i][o4 * 4 + 3] = v.w * qs;
    }
    __syncthreads();
    short* op = wt_ws + (size_t)h * 192 * 64 + (size_t)ot * 64 * 64;
    for (int e = tid; e < 1024; e += 256) {
        const int o = e >> 4, i4 = e & 15;
        short4 s = make_short4(f2bf(tile[i4 * 4 + 0][o]), f2bf(tile[i4 * 4 + 1][o]),
                               f2bf(tile[i4 * 4 + 2][o]), f2bf(tile[i4 * 4 + 3][o]));
        *reinterpret_cast<short4*>(op + o * 64 + i4 * 4) = s;
    }
}

// ---------------------------------------------------------------------------
// Kernel 1: routed QKV projection, MFMA, LDS-roundtrip epilogue for fully
// coalesced stores. q,k -> [bh][T][64]; v -> chunk-tiled transpose
// [bh][ct=16][d=64][t=64]. q pre-scaled by 0.125*log2e (via wprep).
// ---------------------------------------------------------------------------
__global__ __launch_bounds__(256) void proj_kernel(
    const float* __restrict__ x, const short* __restrict__ wt_ws,
    short* __restrict__ qw, short* __restrict__ kw, short* __restrict__ vt)
{
    __shared__ short buf[64 * LD + 192 * LD];   // 36864 B, aliased stage/epilogue
    short* ax = buf;                 // stage: x tile [t][i]
    short* wt = buf + 64 * LD;       // stage: W^T    [o][i]
    short* eq = buf;                 // epi: q [t][d]
    short* ek = buf + 64 * LD;       // epi: k [t][d]
    short* ev = buf + 128 * LD;      // epi: v [d][t]

    const int h = blockIdx.y;
    const int tid = threadIdx.x;
    const int t0g = blockIdx.x * 64;
    const int b = t0g / T, t0 = t0g % T;
    const int bh = b * H + h;
    const int ct = t0 >> 6;

    const float* xp = x + ((size_t)(b * T + t0) * H + h) * D;
    for (int e4 = tid; e4 < 64 * 16; e4 += 256) {
        const int row = e4 >> 4, i4 = e4 & 15;
        float4 v = *reinterpret_cast<const float4*>(xp + (size_t)row * H * D + i4 * 4);
        *reinterpret_cast<short4*>(&ax[row * LD + i4 * 4]) =
            make_short4(f2bf(v.x), f2bf(v.y), f2bf(v.z), f2bf(v.w));
    }
    const short* wtp = wt_ws + (size_t)h * 192 * 64;
    for (int e8 = tid; e8 < 192 * 8; e8 += 256) {
        const int row = e8 >> 3, c8 = e8 & 7;
        *reinterpret_cast<uint4*>(&wt[row * LD + c8 * 8]) =
            *reinterpret_cast<const uint4*>(wtp + (size_t)row * 64 + c8 * 8);
    }
    __syncthreads();

    const int wv = tid >> 6, lane = tid & 63, quad = lane >> 4, c = lane & 15;
    s16x8 af[4][2];
    #pragma unroll
    for (int mb = 0; mb < 4; ++mb)
        #pragma unroll
        for (int ks = 0; ks < 2; ++ks)
            af[mb][ks] = *reinterpret_cast<const s16x8*>(
                &ax[(mb * 16 + c) * LD + ks * 32 + quad * 8]);

    f32x4 acc[4][3];
    #pragma unroll
    for (int mb = 0; mb < 4; ++mb)
        #pragma unroll
        for (int nb = 0; nb < 3; ++nb)
            acc[mb][nb] = (f32x4){0.f, 0.f, 0.f, 0.f};

    #pragma unroll
    for (int nb = 0; nb < 3; ++nb) {
        const int o16 = nb * 4 + wv;             // wave handles one q, k, v slice
        #pragma unroll
        for (int ks = 0; ks < 2; ++ks) {
            s16x8 bf = *reinterpret_cast<const s16x8*>(
                &wt[(o16 * 16 + c) * LD + ks * 32 + quad * 8]);
            #pragma unroll
            for (int mb = 0; mb < 4; ++mb)
                acc[mb][nb] = __builtin_amdgcn_mfma_f32_16x16x32_bf16(
                    af[mb][ks], bf, acc[mb][nb], 0, 0, 0);
        }
    }
    __syncthreads();   // stage buffers dead; reuse LDS for epilogue

    const int d = wv * 16 + c;
    #pragma unroll
    for (int mb = 0; mb < 4; ++mb) {
        #pragma unroll
        for (int reg = 0; reg < 4; ++reg) {
            const int tl = mb * 16 + quad * 4 + reg;
            eq[tl * LD + d] = f2bf(acc[mb][0][reg]);
            ek[tl * LD + d] = f2bf(acc[mb][1][reg]);
        }
        short4 sv = make_short4(f2bf(acc[mb][2][0]), f2bf(acc[mb][2][1]),
                                f2bf(acc[mb][2][2]), f2bf(acc[mb][2][3]));
        *reinterpret_cast<short4*>(&ev[d * LD + mb * 16 + quad * 4]) = sv;
    }
    __syncthreads();

    // coalesced stores: a row is 64 shorts = 128 B = EIGHT 16B segments.
    for (int e = tid; e < 512; e += 256) {
        const int r = e >> 3, seg = e & 7;
        uint4 vq = *reinterpret_cast<const uint4*>(&eq[r * LD + seg * 8]);
        uint4 vk = *reinterpret_cast<const uint4*>(&ek[r * LD + seg * 8]);
        uint4 vv = *reinterpret_cast<const uint4*>(&ev[r * LD + seg * 8]);
        *reinterpret_cast<uint4*>(qw + ((size_t)bh * T + t0 + r) * 64 + seg * 8) = vq;
        *reinterpret_cast<uint4*>(kw + ((size_t)bh * T + t0 + r) * 64 + seg * 8) = vk;
        *reinterpret_cast<uint4*>(vt + (((size_t)bh * 16 + ct) * 64 + r) * 64 + seg * 8) = vv;
    }
}

// ---------------------------------------------------------------------------
// Kernel 2: causal attention, R7 structure (4 waves x 16 q-rows, single-
// buffered K/V LDS staging, transposed-score MFMA, static-max base-2
// softmax). NEW: chunk-range work units — qt>=8 split across 2 blocks;
// split blocks emit unnormalized fp32 O-partial + l-partial to workspace.
// ---------------------------------------------------------------------------
__global__ __launch_bounds__(256) void attn_kernel(
    const short* __restrict__ qw, const short* __restrict__ kw,
    const short* __restrict__ vt, float* __restrict__ out,
    float* __restrict__ po, float* __restrict__ pl)
{
    __shared__ short lk[64 * LD];        // 9216 B : K chunk   [s][d]
    __shared__ short lv[64 * LD];        // 9216 B : V^T chunk [d][s]
    __shared__ short lp[4][16 * LD];     // 9216 B : P, wave-private [r][s]

    const int idx = blockIdx.x;
    const int bh = idx % 48;
    const int4 u = UNITS[idx / 48];
    const int qt = u.x, ch0 = u.y, ch1 = u.z, slot = u.w;
    const int b = bh / H, h = bh % H;
    const int tid = threadIdx.x, wv = tid >> 6, lane = tid & 63;
    const int quad = lane >> 4, c = lane & 15;
    const int r0 = qt * 64;

    // Q fragments (B-operand: rows of Q, n = c): contiguous 16B, once per block
    s16x8 qf[2];
    {
        const short* qp = qw + ((size_t)bh * T + r0 + wv * 16 + c) * 64;
        qf[0] = *reinterpret_cast<const s16x8*>(qp + quad * 8);
        qf[1] = *reinterpret_cast<const s16x8*>(qp + 32 + quad * 8);
    }

    f32x4 oacc[4];
    #pragma unroll
    for (int cb = 0; cb < 4; ++cb) oacc[cb] = (f32x4){0.f, 0.f, 0.f, 0.f};
    float l_run = 0.f;
    short* lpw = lp[wv];

    for (int ch = ch0; ch <= ch1; ++ch) {
        __syncthreads();
        const short* kp = kw + ((size_t)bh * T + ch * 64) * 64;
        const short* vp = vt + (((size_t)bh * 16 + ch) * 64) * 64;
        for (int e8 = tid; e8 < 512; e8 += 256) {
            const int r = e8 >> 3, c8 = e8 & 7;
            *reinterpret_cast<uint4*>(&lk[r * LD + c8 * 8]) =
                *reinterpret_cast<const uint4*>(kp + r * 64 + c8 * 8);
            *reinterpret_cast<uint4*>(&lv[r * LD + c8 * 8]) =
                *reinterpret_cast<const uint4*>(vp + r * 64 + c8 * 8);
        }
        __syncthreads();

        // S^T tiles: rows s (quad*4+reg), cols r (c). A = K rows, B = Q rows.
        const bool diag = (ch == qt);
        float lsum = 0.f;
        #pragma unroll
        for (int st = 0; st < 4; ++st) {
            s16x8 a0 = *reinterpret_cast<const s16x8*>(
                &lk[(st * 16 + c) * LD + quad * 8]);
            s16x8 a1 = *reinterpret_cast<const s16x8*>(
                &lk[(st * 16 + c) * LD + 32 + quad * 8]);
            f32x4 sacc = (f32x4){0.f, 0.f, 0.f, 0.f};
            sacc = __builtin_amdgcn_mfma_f32_16x16x32_bf16(a0, qf[0], sacc, 0, 0, 0);
            sacc = __builtin_amdgcn_mfma_f32_16x16x32_bf16(a1, qf[1], sacc, 0, 0, 0);
            if (diag) {
                #pragma unroll
                for (int reg = 0; reg < 4; ++reg)
                    if (st * 16 + quad * 4 + reg > wv * 16 + c) sacc[reg] = -1e30f;
            }
            float p0 = __builtin_amdgcn_exp2f(sacc[0] - 8.0f);
            float p1 = __builtin_amdgcn_exp2f(sacc[1] - 8.0f);
            float p2 = __builtin_amdgcn_exp2f(sacc[2] - 8.0f);
            float p3 = __builtin_amdgcn_exp2f(sacc[3] - 8.0f);
            lsum += (p0 + p1) + (p2 + p3);
            *reinterpret_cast<short4*>(&lpw[c * LD + st * 16 + quad * 4]) =
                make_short4(f2bf_trunc(p0), f2bf_trunc(p1),
                            f2bf_trunc(p2), f2bf_trunc(p3));
        }
        lsum += __shfl_xor(lsum, 16);
        lsum += __shfl_xor(lsum, 32);
        l_run += lsum;                      // full row-sum for q-row wv*16 + c

        // O += P V : A = P rows (contiguous from lp, same-wave DS in-order)
        #pragma unroll
        for (int ks2 = 0; ks2 < 2; ++ks2) {
            s16x8 pa = *reinterpret_cast<const s16x8*>(
                &lpw[c * LD + ks2 * 32 + quad * 8]);
            #pragma unroll
            for (int cb = 0; cb < 4; ++cb) {
                s16x8 bf = *reinterpret_cast<const s16x8*>(
                    &lv[(cb * 16 + c) * LD + ks2 * 32 + quad * 8]);
                oacc[cb] = __builtin_amdgcn_mfma_f32_16x16x32_bf16(
                    pa, bf, oacc[cb], 0, 0, 0);
            }
        }
    }

    if (slot < 0) {
        // direct: normalize and write to out
        float linv[4];
        #pragma unroll
        for (int reg = 0; reg < 4; ++reg)
            linv[reg] = 1.0f / __shfl(l_run, quad * 4 + reg);
        #pragma unroll
        for (int cb = 0; cb < 4; ++cb)
            #pragma unroll
            for (int reg = 0; reg < 4; ++reg) {
                const int t = r0 + wv * 16 + quad * 4 + reg;
                out[((size_t)(b * T + t) * H + h) * D + cb * 16 + c] =
                    oacc[cb][reg] * linv[reg];
            }
    } else {
        // partial: unnormalized O + l to workspace
        float* pob = po + (((size_t)bh * 16 + slot) * 64) * 64;
        #pragma unroll
        for (int cb = 0; cb < 4; ++cb)
            #pragma unroll
            for (int reg = 0; reg < 4; ++reg)
                pob[(size_t)(wv * 16 + quad * 4 + reg) * 64 + cb * 16 + c] =
                    oacc[cb][reg];
        if (quad == 0)
            pl[((size_t)bh * 16 + slot) * 64 + wv * 16 + c] = l_run;
    }
}

// ---------------------------------------------------------------------------
// Kernel 3: merge split partials for qt in [8,15]:
// out = (Oa + Ob) / (la + lb). 384 blocks x 256 threads, 4 threads per row.
// ---------------------------------------------------------------------------
__global__ __launch_bounds__(256) void merge_kernel(
    const float* __restrict__ po, const float* __restrict__ pl,
    float* __restrict__ out)
{
    const int m = blockIdx.x;
    const int bh = m % 48, qi = m / 48;          // qi 0..7 -> qt = qi+8
    const int b = bh / H, h = bh % H;
    const int sa = qi * 2, sb = sa + 1;
    const int tid = threadIdx.x;
    const int r = tid >> 2, dseg = (tid & 3) * 16;

    const float la = pl[((size_t)bh * 16 + sa) * 64 + r]
                   + pl[((size_t)bh * 16 + sb) * 64 + r];
    const float inv = 1.0f / la;
    const float* pa = po + (((size_t)bh * 16 + sa) * 64 + r) * 64 + dseg;
    const float* pb = po + (((size_t)bh * 16 + sb) * 64 + r) * 64 + dseg;
    const int t = (qi + 8) * 64 + r;
    float* op = out + ((size_t)(b * T + t) * H + h) * D + dseg;
    #pragma unroll
    for (int j = 0; j < 4; ++j) {
        float4 va = *reinterpret_cast<const float4*>(pa + j * 4);
        float4 vb = *reinterpret_cast<const float4*>(pb + j * 4);
        float4 vo = make_float4((va.x + vb.x) * inv, (va.y + vb.y) * inv,
                                (va.z + vb.z) * inv, (va.w + vb.w) * inv);
        *reinterpret_cast<float4*>(op + j * 4) = vo;
    }
}

extern "C" void kernel_launch(void* const* d_in, const int* in_sizes, int n_in,
                              void* d_out, int out_size, void* d_ws, size_t ws_size,
                              hipStream_t stream) {
    const float* x   = (const float*)d_in[0];   // [B,T,K,N,D] fp32
    const float* W   = (const float*)d_in[1];   // [K,N,D,3D] fp32
    const int*   s2h = (const int*)d_in[2];     // [K,N] int32
    float* out = (float*)d_out;                 // [B,T,K,N,D] fp32

    short* wt_ws = (short*)d_ws;                       // [12][192][64] bf16
    short* qw    = wt_ws + (size_t)12 * 192 * 64;      // [bh][T][64] (pre-scaled)
    short* kw    = qw + (size_t)B * H * T * D;         // [bh][T][64]
    short* vt    = kw + (size_t)B * H * T * D;         // [bh][16][64][64] chunked V^T
    float* po    = (float*)(vt + (size_t)B * H * 16 * 64 * 64);  // [bh][16][64][64]
    float* pl    = po + (size_t)B * H * 16 * 64 * 64;            // [bh][16][64]

    wprep_kernel<<<dim3(H, 3), 256, 0, stream>>>(W, s2h, wt_ws);
    proj_kernel<<<dim3(B * T / 64, H), 256, 0, stream>>>(x, wt_ws, qw, kw, vt);
    attn_kernel<<<dim3(24 * 48), 256, 0, stream>>>(qw, kw, vt, out, po, pl);
    merge_kernel<<<dim3(8 * 48), 256, 0, stream>>>(po, pl, out);
}